// Round 8
// baseline (345.773 us; speedup 1.0000x reference)
//
#include <hip/hip_runtime.h>
#include <hip/hip_bf16.h>

// Problem: B=8, T_OUT=256, T_IN=512, L=128, D_IN=128, D_ATT=128 (f32 in/out).
// R8: scan waves 8->4 (256 thr), each wave does TWO 16-unit jobs sharing one
// set of B-frags: per-CU LDS-pipe load halves (16 b128/step), VALU queue
// halves, 2 independent gate chains/lane give ILP over the transcendental
// latency. MFMA work unchanged. Keys GEMM still fused (blocks 2-257).
//
// ws layout (float elements):
#define XZ_OFF   1048576   // f16[8*256*512] region (2 MB)
#define KEYS_OFF 2097152   // f32[8*512*128]
#define X_OFF    2621440   // f16[8*256*128] region
// out layout (f32): out(8,256,256) @0, h(8,128) @524288, c(8,128) @525312
#define OUT_H    524288
#define OUT_C    525312

#define LDS_BARRIER() __asm__ __volatile__("s_waitcnt lgkmcnt(0)\n\ts_barrier" ::: "memory")

typedef _Float16 f16x8 __attribute__((ext_vector_type(8)));
typedef float fx4 __attribute__((ext_vector_type(4)));

__device__ __forceinline__ float fast_rcp(float x) { return __builtin_amdgcn_rcpf(x); }
__device__ __forceinline__ float fast_sig(float v) { return fast_rcp(1.f + __expf(-v)); }
__device__ __forceinline__ float fast_tanh(float v) { return 2.f * fast_rcp(1.f + __expf(-2.f * v)) - 1.f; }

// ---------------- Kernel 1: xz = inputs @ Wk + bias, f16 [t][b][u][gate] ----------------
__global__ __launch_bounds__(256)
void xz_prologue(const float* __restrict__ inp, const float* __restrict__ Wk,
                 const float* __restrict__ bias, float* __restrict__ ws) {
  _Float16* xz16 = (_Float16*)(ws + XZ_OFF);
  __shared__ float ar[8][128];
  const int tid = threadIdx.x;
  const int row0 = blockIdx.x * 8;
  for (int i = tid; i < 8 * 128; i += 256) ar[i >> 7][i & 127] = inp[row0 * 128 + i];
  __syncthreads();
  float acc[8][2];
  const float bb0 = bias[tid], bb1 = bias[tid + 256];
#pragma unroll
  for (int r = 0; r < 8; ++r) { acc[r][0] = bb0; acc[r][1] = bb1; }
  for (int d = 0; d < 128; d += 4) {
    float w0a = Wk[(d + 0) * 512 + tid], w0b = Wk[(d + 0) * 512 + tid + 256];
    float w1a = Wk[(d + 1) * 512 + tid], w1b = Wk[(d + 1) * 512 + tid + 256];
    float w2a = Wk[(d + 2) * 512 + tid], w2b = Wk[(d + 2) * 512 + tid + 256];
    float w3a = Wk[(d + 3) * 512 + tid], w3b = Wk[(d + 3) * 512 + tid + 256];
#pragma unroll
    for (int r = 0; r < 8; ++r) {
      float4 a4 = *(const float4*)&ar[r][d];
      acc[r][0] += a4.x * w0a + a4.y * w1a + a4.z * w2a + a4.w * w3a;
      acc[r][1] += a4.x * w0b + a4.y * w1b + a4.z * w2b + a4.w * w3b;
    }
  }
  // Wk col = g*128 + u (Keras gate blocks) -> ((t*8+b)*128+u)*4+g
  const int u = tid & 127, g0 = tid >> 7;
#pragma unroll
  for (int r = 0; r < 8; ++r) {
    const int row = row0 + r, b = row >> 8, t = row & 255;
    const int base = ((t * 8 + b) * 128 + u) * 4;
    xz16[base + g0]     = (_Float16)acc[r][0];
    xz16[base + g0 + 2] = (_Float16)acc[r][1];
  }
}

// ---------------- Kernel 2: LSTM scan v7 (4 waves, dual jobs) + keys GEMM ----------------
// Blocks 0-1: scan (4 batches each, 4 waves). Blocks 2-257: keys GEMM.
// Wave w covers units [16w,16w+16) (job 0) and [64+16w,64+16w+16) (job 1).
// Row-map per job: m = 4*du + g; MFMA i covers units base+4i+du. Lane (q,p):
// own i = p>>2, unit = base + 4*(p>>2) + q, gates = D-regs 0..3, batch = p&3.
__global__ __launch_bounds__(256, 1)
void lstm_scan(const float* __restrict__ Wrf, const float* __restrict__ att,
               const float* __restrict__ W1, const float* __restrict__ b1,
               const float* __restrict__ ws, float* __restrict__ out) {
  __shared__ _Float16 hb[2][552];       // 4 rows x stride 136, dbuf
  __shared__ float ar[16][128];         // keys staging (blocks >= 2 only)
  const int tid = threadIdx.x;

  if (blockIdx.x >= 2) {
    // ---- keys GEMM: 16 rows, 256 threads ----
    float* keys = (float*)ws + KEYS_OFF;
    const int row0 = (blockIdx.x - 2) * 16;
    for (int i = tid; i < 16 * 128; i += 256) ar[i >> 7][i & 127] = att[row0 * 128 + i];
    __syncthreads();
    const int l = tid & 127, r0 = tid >> 7;  // r0 in 0..1
    float acc[8];
    const float bl = b1[l];
#pragma unroll
    for (int i = 0; i < 8; ++i) acc[i] = bl;
    for (int d = 0; d < 128; d += 4) {
      float w0 = W1[(d + 0) * 128 + l], w1 = W1[(d + 1) * 128 + l];
      float w2 = W1[(d + 2) * 128 + l], w3 = W1[(d + 3) * 128 + l];
#pragma unroll
      for (int i = 0; i < 8; ++i) {
        float4 a4 = *(const float4*)&ar[r0 + 2 * i][d];
        acc[i] += a4.x * w0 + a4.y * w1 + a4.z * w2 + a4.w * w3;
      }
    }
#pragma unroll
    for (int i = 0; i < 8; ++i) keys[(row0 + r0 + 2 * i) * 128 + l] = acc[i];
    return;
  }

  // ---- scan: 4 waves ----
  const _Float16* xz16 = (const _Float16*)(ws + XZ_OFF);
  _Float16* x16 = (_Float16*)((float*)ws + X_OFF);
  const int b_base = blockIdx.x * 4;
  const int w = tid >> 6, lane = tid & 63;
  const int q = lane >> 4, p = lane & 15;
  const int b = p & 3, isel = p >> 2;
  const int u0 = 16 * w + 4 * isel + q;       // job-0 unit
  const int u1 = 64 + u0;                     // job-1 unit
  const int bg = b_base + b;

  // A-frags: afr[jj][i][kt]; col = (p&3)*128 + base(jj) + 4i + (p>>2)
  f16x8 afr[2][4][4];
#pragma unroll
  for (int jj = 0; jj < 2; ++jj) {
    const int base = 64 * jj + 16 * w;
#pragma unroll
    for (int i = 0; i < 4; ++i) {
      const int col = (p & 3) * 128 + base + 4 * i + (p >> 2);
#pragma unroll
      for (int kt = 0; kt < 4; ++kt)
#pragma unroll
        for (int j = 0; j < 8; ++j)
          afr[jj][i][kt][j] = (_Float16)Wrf[(kt * 32 + q * 8 + j) * 512 + col];
    }
  }

  {
    _Float16* hp = &hb[0][0];
    for (int i = tid; i < 2 * 552; i += 256) hp[i] = (_Float16)0.f;
  }
  const fx4 zeroC = {0.f, 0.f, 0.f, 0.f};
  float cst0 = 0.f, cst1 = 0.f, hval0 = 0.f, hval1 = 0.f;
  // xz prefetch, 3 deep x 2 jobs: 8B each, stride 4096 f16 per t
  const _Float16* xp0 = xz16 + (bg * 128 + u0) * 4;
  const _Float16* xp1 = xz16 + (bg * 128 + u1) * 4;
  uint2 pa0 = *(const uint2*)(xp0),        pb0 = *(const uint2*)(xp1);
  uint2 pa1 = *(const uint2*)(xp0 + 4096), pb1 = *(const uint2*)(xp1 + 4096);
  uint2 pa2 = *(const uint2*)(xp0 + 8192), pb2 = *(const uint2*)(xp1 + 8192);
  __syncthreads();

  const int brow = (p & 3) * 136;  // B broadcast: lanes p>=4 mirror p&3
  for (int t = 0; t < 256; ++t) {
    const _Float16* hrow = &hb[t & 1][brow];
    f16x8 bfr[4];
#pragma unroll
    for (int kt = 0; kt < 4; ++kt)
      bfr[kt] = *(const f16x8*)&hrow[kt * 32 + q * 8];
    fx4 acc[2][4];
#pragma unroll
    for (int jj = 0; jj < 2; ++jj)
#pragma unroll
      for (int i = 0; i < 4; ++i)
        acc[jj][i] = __builtin_amdgcn_mfma_f32_16x16x32_f16(afr[jj][i][0], bfr[0], zeroC, 0, 0, 0);
#pragma unroll
    for (int kt = 1; kt < 4; ++kt)
#pragma unroll
      for (int jj = 0; jj < 2; ++jj)
#pragma unroll
        for (int i = 0; i < 4; ++i)
          acc[jj][i] = __builtin_amdgcn_mfma_f32_16x16x32_f16(afr[jj][i][kt], bfr[kt], acc[jj][i], 0, 0, 0);

    // select MFMA i = isel per job (2-bit cndmask tree)
    float z0[4], z1[4];
#pragma unroll
    for (int r = 0; r < 4; ++r) {
      float s01 = (isel & 1) ? acc[0][1][r] : acc[0][0][r];
      float s23 = (isel & 1) ? acc[0][3][r] : acc[0][2][r];
      z0[r] = (isel & 2) ? s23 : s01;
      float t01 = (isel & 1) ? acc[1][1][r] : acc[1][0][r];
      float t23 = (isel & 1) ? acc[1][3][r] : acc[1][2][r];
      z1[r] = (isel & 2) ? t23 : t01;
    }

    uint2 ca = pa0, cb = pb0;
    pa0 = pa1; pa1 = pa2; pb0 = pb1; pb1 = pb2;
    const int t3 = (t + 3 < 256) ? t + 3 : 255;
    pa2 = *(const uint2*)(xp0 + t3 * 4096);
    pb2 = *(const uint2*)(xp1 + t3 * 4096);

    const _Float16* cf0 = (const _Float16*)&ca;
    const _Float16* cf1 = (const _Float16*)&cb;
    // two independent gate chains (ILP over transcendental latency)
    const float zi0 = z0[0] + (float)cf0[0], zf0 = z0[1] + (float)cf0[1];
    const float zg0 = z0[2] + (float)cf0[2], zo0 = z0[3] + (float)cf0[3];
    const float zi1 = z1[0] + (float)cf1[0], zf1 = z1[1] + (float)cf1[1];
    const float zg1 = z1[2] + (float)cf1[2], zo1 = z1[3] + (float)cf1[3];
    cst0 = fast_sig(zf0) * cst0 + fast_sig(zi0) * fast_tanh(zg0);
    cst1 = fast_sig(zf1) * cst1 + fast_sig(zi1) * fast_tanh(zg1);
    hval0 = fast_sig(zo0) * fast_tanh(cst0);
    hval1 = fast_sig(zo1) * fast_tanh(cst1);
    _Float16* hnxt = &hb[(t + 1) & 1][b * 136];
    hnxt[u0] = (_Float16)hval0;
    hnxt[u1] = (_Float16)hval1;
    _Float16* xo = x16 + (bg * 256 + t) * 128;
    xo[u0] = (_Float16)hval0;
    xo[u1] = (_Float16)hval1;
    LDS_BARRIER();  // LDS visibility only; no vmcnt drain
  }
  out[OUT_H + bg * 128 + u0] = hval0;
  out[OUT_H + bg * 128 + u1] = hval1;
  out[OUT_C + bg * 128 + u0] = cst0;
  out[OUT_C + bg * 128 + u1] = cst1;
}

// ---------------- Kernel 3: qproj + scores + softmax + weighted + concat ----------------
// 512 blocks (4 q-rows each) -> 2 blocks/CU for latency hiding.
__global__ __launch_bounds__(256)
void attn_out_k(const float* __restrict__ att, const float* __restrict__ W2c,
                const float* __restrict__ b2c, const float* __restrict__ W3c,
                const float* __restrict__ b3c, const float* __restrict__ ws,
                float* __restrict__ out) {
  const float* keys = ws + KEYS_OFF;
  const _Float16* x16 = (const _Float16*)(ws + X_OFF);
  __shared__ float qp[4][128];
  __shared__ float xr[4][128];
  __shared__ float sc[4][512];
  __shared__ float kt[64][129];
  __shared__ float w3s[128];
  const int tid = threadIdx.x;
  const int b = blockIdx.x >> 6, q0 = (blockIdx.x & 63) * 4;
  const int l = tid & 127, r0 = tid >> 7;  // r0 in 0..1
  if (tid < 128) w3s[tid] = W3c[tid];
  for (int i = tid; i < 4 * 128; i += 256)
    xr[i >> 7][i & 127] = (float)x16[(b * 256 + q0) * 128 + i];
  __syncthreads();
  {
    float qa[2];
    const float bl = b2c[l];
    qa[0] = bl; qa[1] = bl;
    for (int d = 0; d < 128; d += 4) {
      float w0 = W2c[(d + 0) * 128 + l], w1 = W2c[(d + 1) * 128 + l];
      float w2v = W2c[(d + 2) * 128 + l], w3v = W2c[(d + 3) * 128 + l];
#pragma unroll
      for (int i = 0; i < 2; ++i) {
        float4 a4 = *(const float4*)&xr[r0 + 2 * i][d];
        qa[i] += a4.x * w0 + a4.y * w1 + a4.z * w2v + a4.w * w3v;
      }
    }
#pragma unroll
    for (int i = 0; i < 2; ++i) {
      int rr = r0 + 2 * i;
      qp[rr][l] = qa[i];
      out[(b * 256 + q0 + rr) * 256 + l] = xr[rr][l];
    }
  }
  const float b3v = b3c[0];
  for (int kt0 = 0; kt0 < 512; kt0 += 64) {
    __syncthreads();
    for (int i = tid; i < 64 * 128; i += 256)
      kt[i >> 7][i & 127] = keys[(b * 512 + kt0 + (i >> 7)) * 128 + (i & 127)];
    __syncthreads();
    {
      const int rr = tid >> 6, k = tid & 63;
      float acc = 0.f;
      for (int ll = 0; ll < 128; ll += 4) {
        float4 q4 = *(const float4*)&qp[rr][ll];
        float4 w4 = *(const float4*)&w3s[ll];
        acc += fast_tanh(kt[k][ll + 0] + q4.x) * w4.x
             + fast_tanh(kt[k][ll + 1] + q4.y) * w4.y
             + fast_tanh(kt[k][ll + 2] + q4.z) * w4.z
             + fast_tanh(kt[k][ll + 3] + q4.w) * w4.w;
      }
      sc[rr][kt0 + k] = acc + b3v;
    }
  }
  __syncthreads();
  {
    const int wave = tid >> 6, lane = tid & 63;  // wave w owns row w
    float v[8];
#pragma unroll
    for (int i = 0; i < 8; ++i) v[i] = sc[wave][lane + i * 64];
    float m = v[0];
#pragma unroll
    for (int i = 1; i < 8; ++i) m = fmaxf(m, v[i]);
#pragma unroll
    for (int off = 32; off > 0; off >>= 1) m = fmaxf(m, __shfl_xor(m, off));
    float e[8], s = 0.f;
#pragma unroll
    for (int i = 0; i < 8; ++i) { e[i] = __expf(v[i] - m); s += e[i]; }
#pragma unroll
    for (int off = 32; off > 0; off >>= 1) s += __shfl_xor(s, off);
    const float inv = fast_rcp(s);
#pragma unroll
    for (int i = 0; i < 8; ++i) sc[wave][lane + i * 64] = e[i] * inv;
  }
  __syncthreads();
  {
    const float* attb = att + b * 512 * 128;
    float wa[2] = {0.f, 0.f};
    for (int k = 0; k < 512; k += 4) {
      float a0 = attb[(k + 0) * 128 + l];
      float a1 = attb[(k + 1) * 128 + l];
      float a2 = attb[(k + 2) * 128 + l];
      float a3 = attb[(k + 3) * 128 + l];
#pragma unroll
      for (int i = 0; i < 2; ++i) {
        float4 p4 = *(const float4*)&sc[r0 + 2 * i][k];
        wa[i] += p4.x * a0 + p4.y * a1 + p4.z * a2 + p4.w * a3;
      }
    }
#pragma unroll
    for (int i = 0; i < 2; ++i)
      out[(b * 256 + q0 + r0 + 2 * i) * 256 + 128 + l] = wa[i];
  }
}

extern "C" void kernel_launch(void* const* d_in, const int* in_sizes, int n_in,
                              void* d_out, int out_size, void* d_ws, size_t ws_size,
                              hipStream_t stream) {
  const float* inputs   = (const float*)d_in[0];
  const float* attended = (const float*)d_in[1];
  const float* Wk       = (const float*)d_in[2];
  const float* Wr       = (const float*)d_in[3];
  const float* bias     = (const float*)d_in[4];
  const float* W1       = (const float*)d_in[5];
  const float* b1       = (const float*)d_in[6];
  const float* W2       = (const float*)d_in[7];
  const float* b2       = (const float*)d_in[8];
  const float* W3       = (const float*)d_in[9];
  const float* b3       = (const float*)d_in[10];
  float* out = (float*)d_out;
  float* ws = (float*)d_ws;

  hipLaunchKernelGGL(xz_prologue, dim3(256), dim3(256), 0, stream, inputs, Wk, bias, ws);
  hipLaunchKernelGGL(lstm_scan, dim3(258), dim3(256), 0, stream,
                     Wr, attended, W1, b1, ws, out);
  hipLaunchKernelGGL(attn_out_k, dim3(512), dim3(256), 0, stream,
                     attended, W2, b2, W3, b3, ws, out);
}